// Round 5
// baseline (320.741 us; speedup 1.0000x reference)
//
#include <hip/hip_runtime.h>

// Problem constants
#define BB 32
#define NN 1000
#define HH 256
#define DD 128
#define EE 512000
#define NB (BB * NN) // 32000
#define SCAN_B 125   // 125 * 256 == NB

// Workspace layout (dword offsets)
#define DEGO_OFF 0                        // int[NB]
#define DEGI_OFF (NB)                     // int[NB]
#define ROWS_OFF (2 * NB)                 // int[NB+1]
#define CURS_OFF (3 * NB + 8)             // int[NB]
#define SSRC_OFF (4 * NB + 8)             // int[EE]
#define DSO_OFF (4 * NB + 8 + EE)         // float[NB]
#define DSI_OFF (5 * NB + 8 + EE)         // float[NB]
#define GATE_OFF (6 * NB + 8 + EE)        // float[4*BB*HH]
#define LOCE_OFF (GATE_OFF + 4 * BB * HH) // int[NB]
#define BSUM_OFF (LOCE_OFF + NB)          // int[128]
#define WGB_OFF (BSUM_OFF + 128)          // bf16[HH*HH] = 32768 dwords
#define HW_OFF (WGB_OFF + (HH * HH) / 2)  // bf16[NB*HH] = 4096000 dwords

using bf16x8 = __attribute__((ext_vector_type(8))) short;
using f32x4 = __attribute__((ext_vector_type(4))) float;

__device__ inline unsigned short f2bf(float x) {  // RNE fp32 -> bf16
    unsigned u = __float_as_uint(x);
    return (unsigned short)((u + 0x7FFFu + ((u >> 16) & 1u)) >> 16);
}
__device__ inline float bf2f_lo(unsigned u) {  // low 16 bits -> float
    return __uint_as_float(u << 16);
}
__device__ inline float bf2f_hi(unsigned u) {  // high 16 bits -> float
    return __uint_as_float(u & 0xFFFF0000u);
}

// ---------------------------------------------------------------------------
// K_A (fused): [0,2000) degree histogram | [2000,2256) Wg repack | [2256,2288) gates
__global__ __launch_bounds__(256) void k_pre(
    const int* __restrict__ src, const int* __restrict__ dst,
    int* __restrict__ deg_out, int* __restrict__ deg_in,
    const float* __restrict__ Wg, unsigned short* __restrict__ wgb,
    const float* __restrict__ x, const float* __restrict__ Wi,
    const float* __restrict__ bi, const float* __restrict__ Wf,
    const float* __restrict__ bf_, const float* __restrict__ Wo,
    const float* __restrict__ bo, const float* __restrict__ Wc,
    const float* __restrict__ bc, const float* __restrict__ bg,
    float* __restrict__ gates) {
    __shared__ float xs[DD];
    int bid = blockIdx.x;
    int t = threadIdx.x;
    if (bid < 2000) {
        int e = bid * 256 + t;
        atomicAdd(&deg_out[src[e]], 1);
        atomicAdd(&deg_in[dst[e]], 1);
    } else if (bid < 2256) {
        // repack Wg into bf16 MFMA-B fragment order
        int o = (bid - 2000) * 256 + t; // 0..65535
        int j = o & 7;
        int c = o >> 3;
        int lane = c & 63;
        int nt = (c >> 6) & 15;
        int kk = c >> 10;
        int k = kk * 32 + (lane >> 4) * 8 + j;
        int n = nt * 16 + (lane & 15);
        wgb[o] = f2bf(Wg[k * HH + n]);
    } else {
        // gate projections; bg folded into every gate bias
        int b = bid - 2256;
        int j = t;
        if (j < DD) xs[j] = x[b * DD + j];
        __syncthreads();
        float bgj = bg[j];
        float ai = bi[j] + bgj, af = bf_[j] + bgj, ao = bo[j] + bgj,
              ac = bc[j] + bgj;
#pragma unroll 4
        for (int k = 0; k < DD; k++) {
            float xv = xs[k];
            ai += xv * Wi[k * HH + j];
            af += xv * Wf[k * HH + j];
            ao += xv * Wo[k * HH + j];
            ac += xv * Wc[k * HH + j];
        }
        gates[0 * BB * HH + b * HH + j] = ai;
        gates[1 * BB * HH + b * HH + j] = af;
        gates[2 * BB * HH + b * HH + j] = ao;
        gates[3 * BB * HH + b * HH + j] = ac;
    }
}

// K_B: per-block exclusive scan of deg_in; block sums; rsqrt scales.
__global__ __launch_bounds__(256) void k_scan1(
    const int* __restrict__ deg_in, const int* __restrict__ deg_out,
    int* __restrict__ loce, int* __restrict__ bsum, float* __restrict__ dso,
    float* __restrict__ dsi) {
    __shared__ int sm[256];
    int b = blockIdx.x, t = threadIdx.x;
    int idx = b * 256 + t;
    int d = deg_in[idx];
    sm[t] = d;
    __syncthreads();
    for (int off = 1; off < 256; off <<= 1) {
        int v = (t >= off) ? sm[t - off] : 0;
        __syncthreads();
        sm[t] += v;
        __syncthreads();
    }
    loce[idx] = sm[t] - d;
    if (t == 255) bsum[b] = sm[255];
    dsi[idx] = rsqrtf((float)max(d, 1));
    dso[idx] = rsqrtf((float)max(deg_out[idx], 1));
}

// K_C: each block reduces bsum[0..b) for its offset, emits row_start/cursor.
__global__ __launch_bounds__(256) void k_scan3(const int* __restrict__ loce,
                                               const int* __restrict__ bsum,
                                               int* __restrict__ row_start,
                                               int* __restrict__ cursor) {
    __shared__ int sm[256];
    int b = blockIdx.x, t = threadIdx.x;
    sm[t] = (t < b) ? bsum[t] : 0; // b <= 124 < 256
    __syncthreads();
    for (int off = 128; off >= 1; off >>= 1) {
        if (t < off) sm[t] += sm[t + off];
        __syncthreads();
    }
    int boffb = sm[0];
    int idx = b * 256 + t;
    int e = loce[idx] + boffb;
    row_start[idx] = e;
    cursor[idx] = e;
    if (idx == 0) row_start[NB] = EE;
}

// K_D: counting-sort edges by dst (512k int atomics)
__global__ __launch_bounds__(256) void k_binsort(const int* __restrict__ src,
                                                 const int* __restrict__ dst,
                                                 int* __restrict__ cursor,
                                                 int* __restrict__ sorted_src) {
    int e = blockIdx.x * 256 + threadIdx.x;
    if (e < EE) {
        int pos = atomicAdd(&cursor[dst[e]], 1);
        sorted_src[pos] = src[e];
    }
}

// K_E: hW = (h_prev * dso[:,None]) @ Wg via bf16 MFMA, bf16 out.
// 512 threads = 8 waves: wave w -> row-tile (w&3)*16, col-half (w>>2)*128.
// Epilogue: C-layout -> padded LDS tile -> coalesced dwordx4 stores.
#define LDS_STRIDE 264 // ushorts; 528 B rows, 16B-aligned
__global__ __launch_bounds__(512) void k_hw(const float* __restrict__ h,
                                            const float* __restrict__ dso,
                                            const unsigned short* __restrict__ wgb,
                                            unsigned short* __restrict__ hw) {
    __shared__ unsigned short tile[64 * LDS_STRIDE]; // ~33.8 KB
    int t = threadIdx.x;
    int lane = t & 63;
    int w = t >> 6;
    int wt = w & 3;  // row tile
    int ch = w >> 2; // col half
    int quad = lane >> 4;
    int mrow = lane & 15;
    int r0 = blockIdx.x * 64 + wt * 16;
    int row = r0 + mrow;
    float sc = dso[row];

    f32x4 acc[8];
#pragma unroll
    for (int nt = 0; nt < 8; nt++) acc[nt] = (f32x4){0.f, 0.f, 0.f, 0.f};

#pragma unroll 1
    for (int kk = 0; kk < 8; kk++) {
        const float* ap = h + (size_t)row * HH + kk * 32 + quad * 8;
        float4 a0 = *(const float4*)ap;
        float4 a1 = *(const float4*)(ap + 4);
        bf16x8 af;
        af[0] = (short)f2bf(a0.x * sc);
        af[1] = (short)f2bf(a0.y * sc);
        af[2] = (short)f2bf(a0.z * sc);
        af[3] = (short)f2bf(a0.w * sc);
        af[4] = (short)f2bf(a1.x * sc);
        af[5] = (short)f2bf(a1.y * sc);
        af[6] = (short)f2bf(a1.z * sc);
        af[7] = (short)f2bf(a1.w * sc);
#pragma unroll
        for (int ntl = 0; ntl < 8; ntl++) {
            int nt = ch * 8 + ntl;
            bf16x8 bf =
                *(const bf16x8*)(wgb + (((kk * 16 + nt) * 64 + lane) << 3));
            acc[ntl] =
                __builtin_amdgcn_mfma_f32_16x16x32_bf16(af, bf, acc[ntl], 0, 0, 0);
        }
    }

    // C/D layout: row = quad*4+reg, col = nt*16+mrow  -> LDS
#pragma unroll
    for (int ntl = 0; ntl < 8; ntl++) {
        int lcol = ch * 128 + ntl * 16 + mrow;
#pragma unroll
        for (int reg = 0; reg < 4; reg++) {
            int lrow = wt * 16 + quad * 4 + reg;
            tile[lrow * LDS_STRIDE + lcol] = f2bf(acc[ntl][reg]);
        }
    }
    __syncthreads();

    // Coalesced store: 2048 chunks of 16B
    size_t base = (size_t)blockIdx.x * 64 * HH;
#pragma unroll
    for (int p = 0; p < 4; p++) {
        int c = p * 512 + t;
        int grow = c >> 5;
        int coloff = (c & 31) * 8;
        uint4 v = *(const uint4*)(&tile[grow * LDS_STRIDE + coloff]);
        *(uint4*)(hw + base + (size_t)grow * HH + coloff) = v;
    }
}

// K_F: CSR gather of hW rows + LSTM epilogue.
// One wave per node. Lanes 0-31: even edges, lanes 32-63: odd edges.
// Each lane loads 16B (8 bf16 cols) per edge; halves merged via shfl(lane^32).
__device__ inline void lstm1(float hc, float gi, float gf, float go, float gc,
                             float cp, float& ho, float& co) {
    float pi = gi + hc, pf = gf + hc, po = go + hc, pc = gc + hc;
    float it = 1.f / (1.f + __expf(-pi));
    float ft = 1.f / (1.f + __expf(-pf));
    float ot = 1.f / (1.f + __expf(-po));
    float e2 = __expf(2.f * pc);
    float ctl = (e2 - 1.f) / (e2 + 1.f);
    float ct = ft * cp + it * ctl;
    float e2c = __expf(2.f * ct);
    ho = ot * (e2c - 1.f) / (e2c + 1.f);
    co = ct;
}

__global__ __launch_bounds__(256) void k_out(
    const unsigned short* __restrict__ hw, const int* __restrict__ sorted_src,
    const int* __restrict__ row_start, const float* __restrict__ dsi,
    const float* __restrict__ gates, const float* __restrict__ c_prev,
    float* __restrict__ h_out, float* __restrict__ c_out) {
    int t = threadIdx.x;
    int lane = t & 63;
    int w = t >> 6;
    int node = blockIdx.x * 4 + w;
    int beg = row_start[node];
    int end = row_start[node + 1];
    int half = lane >> 5;
    int col = (lane & 31) * 8;

    float a0 = 0.f, a1 = 0.f, a2 = 0.f, a3 = 0.f, a4 = 0.f, a5 = 0.f,
          a6 = 0.f, a7 = 0.f;
    int e = beg + half;
    // 4 edges per lane in flight
    for (; e + 6 < end; e += 8) {
        int s0 = sorted_src[e + 0];
        int s1 = sorted_src[e + 2];
        int s2 = sorted_src[e + 4];
        int s3 = sorted_src[e + 6];
        uint4 q0 = *(const uint4*)(hw + (size_t)s0 * HH + col);
        uint4 q1 = *(const uint4*)(hw + (size_t)s1 * HH + col);
        uint4 q2 = *(const uint4*)(hw + (size_t)s2 * HH + col);
        uint4 q3 = *(const uint4*)(hw + (size_t)s3 * HH + col);
        a0 += bf2f_lo(q0.x) + bf2f_lo(q1.x) + bf2f_lo(q2.x) + bf2f_lo(q3.x);
        a1 += bf2f_hi(q0.x) + bf2f_hi(q1.x) + bf2f_hi(q2.x) + bf2f_hi(q3.x);
        a2 += bf2f_lo(q0.y) + bf2f_lo(q1.y) + bf2f_lo(q2.y) + bf2f_lo(q3.y);
        a3 += bf2f_hi(q0.y) + bf2f_hi(q1.y) + bf2f_hi(q2.y) + bf2f_hi(q3.y);
        a4 += bf2f_lo(q0.z) + bf2f_lo(q1.z) + bf2f_lo(q2.z) + bf2f_lo(q3.z);
        a5 += bf2f_hi(q0.z) + bf2f_hi(q1.z) + bf2f_hi(q2.z) + bf2f_hi(q3.z);
        a6 += bf2f_lo(q0.w) + bf2f_lo(q1.w) + bf2f_lo(q2.w) + bf2f_lo(q3.w);
        a7 += bf2f_hi(q0.w) + bf2f_hi(q1.w) + bf2f_hi(q2.w) + bf2f_hi(q3.w);
    }
    for (; e < end; e += 2) {
        int s = sorted_src[e];
        uint4 q = *(const uint4*)(hw + (size_t)s * HH + col);
        a0 += bf2f_lo(q.x);
        a1 += bf2f_hi(q.x);
        a2 += bf2f_lo(q.y);
        a3 += bf2f_hi(q.y);
        a4 += bf2f_lo(q.z);
        a5 += bf2f_hi(q.z);
        a6 += bf2f_lo(q.w);
        a7 += bf2f_hi(q.w);
    }

    // merge the two edge-halves
    a0 += __shfl(a0, lane ^ 32);
    a1 += __shfl(a1, lane ^ 32);
    a2 += __shfl(a2, lane ^ 32);
    a3 += __shfl(a3, lane ^ 32);
    a4 += __shfl(a4, lane ^ 32);
    a5 += __shfl(a5, lane ^ 32);
    a6 += __shfl(a6, lane ^ 32);
    a7 += __shfl(a7, lane ^ 32);

    float si = dsi[node];
    int b = node / NN;
    const float* gbase = gates + b * HH + col;
    float4 gi0 = *(const float4*)(gbase + 0 * BB * HH);
    float4 gi1 = *(const float4*)(gbase + 0 * BB * HH + 4);
    float4 gf0 = *(const float4*)(gbase + 1 * BB * HH);
    float4 gf1 = *(const float4*)(gbase + 1 * BB * HH + 4);
    float4 go0 = *(const float4*)(gbase + 2 * BB * HH);
    float4 go1 = *(const float4*)(gbase + 2 * BB * HH + 4);
    float4 gc0 = *(const float4*)(gbase + 3 * BB * HH);
    float4 gc1 = *(const float4*)(gbase + 3 * BB * HH + 4);
    float4 cp0 = *(const float4*)(c_prev + (size_t)node * HH + col);
    float4 cp1 = *(const float4*)(c_prev + (size_t)node * HH + col + 4);

    float4 ho0, ho1, co0, co1;
    lstm1(a0 * si, gi0.x, gf0.x, go0.x, gc0.x, cp0.x, ho0.x, co0.x);
    lstm1(a1 * si, gi0.y, gf0.y, go0.y, gc0.y, cp0.y, ho0.y, co0.y);
    lstm1(a2 * si, gi0.z, gf0.z, go0.z, gc0.z, cp0.z, ho0.z, co0.z);
    lstm1(a3 * si, gi0.w, gf0.w, go0.w, gc0.w, cp0.w, ho0.w, co0.w);
    lstm1(a4 * si, gi1.x, gf1.x, go1.x, gc1.x, cp1.x, ho1.x, co1.x);
    lstm1(a5 * si, gi1.y, gf1.y, go1.y, gc1.y, cp1.y, ho1.y, co1.y);
    lstm1(a6 * si, gi1.z, gf1.z, go1.z, gc1.z, cp1.z, ho1.z, co1.z);
    lstm1(a7 * si, gi1.w, gf1.w, go1.w, gc1.w, cp1.w, ho1.w, co1.w);

    // half 0 stores h_out, half 1 stores c_out
    float* outp = half ? (c_out + (size_t)node * HH + col)
                       : (h_out + (size_t)node * HH + col);
    *(float4*)outp = half ? co0 : ho0;
    *(float4*)(outp + 4) = half ? co1 : ho1;
}

// ---------------------------------------------------------------------------
extern "C" void kernel_launch(void* const* d_in, const int* in_sizes, int n_in,
                              void* d_out, int out_size, void* d_ws,
                              size_t ws_size, hipStream_t stream) {
    const float* x = (const float*)d_in[0];
    const float* h_prev = (const float*)d_in[1];
    const float* c_prev = (const float*)d_in[2];
    const int* src = (const int*)d_in[3];
    const int* dst = (const int*)d_in[4];
    const float* Wi = (const float*)d_in[5];
    const float* bi = (const float*)d_in[6];
    const float* Wf = (const float*)d_in[7];
    const float* bf_ = (const float*)d_in[8];
    const float* Wo = (const float*)d_in[9];
    const float* bo = (const float*)d_in[10];
    const float* Wc = (const float*)d_in[11];
    const float* bc = (const float*)d_in[12];
    const float* Wg = (const float*)d_in[13];
    const float* bg = (const float*)d_in[14];

    int* wsi = (int*)d_ws;
    float* wsf = (float*)d_ws;
    int* deg_out = wsi + DEGO_OFF;
    int* deg_in = wsi + DEGI_OFF;
    int* row_start = wsi + ROWS_OFF;
    int* cursor = wsi + CURS_OFF;
    int* sorted_src = wsi + SSRC_OFF;
    float* dso = wsf + DSO_OFF;
    float* dsi = wsf + DSI_OFF;
    float* gates = wsf + GATE_OFF;
    int* loce = wsi + LOCE_OFF;
    int* bsum = wsi + BSUM_OFF;
    unsigned short* wgb = (unsigned short*)(wsi + WGB_OFF);
    unsigned short* hw = (unsigned short*)(wsi + HW_OFF);
    float* h_out = (float*)d_out;
    float* c_out = h_out + (size_t)NB * HH;

    hipMemsetAsync(deg_out, 0, (size_t)2 * NB * 4, stream);

    k_pre<<<2288, 256, 0, stream>>>(src, dst, deg_out, deg_in, Wg, wgb, x, Wi,
                                    bi, Wf, bf_, Wo, bo, Wc, bc, bg, gates);
    k_scan1<<<SCAN_B, 256, 0, stream>>>(deg_in, deg_out, loce, bsum, dso, dsi);
    k_scan3<<<SCAN_B, 256, 0, stream>>>(loce, bsum, row_start, cursor);
    k_binsort<<<(EE + 255) / 256, 256, 0, stream>>>(src, dst, cursor,
                                                    sorted_src);
    k_hw<<<NB / 64, 512, 0, stream>>>(h_prev, dso, wgb, hw);
    k_out<<<NB / 4, 256, 0, stream>>>(hw, sorted_src, row_start, dsi, gates,
                                      c_prev, h_out, c_out);
}